// Round 9
// baseline (5724.488 us; speedup 1.0000x reference)
//
#include <hip/hip_runtime.h>

// Problem constants
#define Hh    8
#define DMm   512
#define HDd   64
#define CBc   32
#define SBs   64
#define WINSZ 512
#define TOPKk 16
#define NEGF  (-1e30f)
#define Bb    2
#define Ss    4096
#define NCc   128   // S/CB
#define NSs   64    // S/SB
#define SCALE 0.125f

// Workspace layout (float offsets) — intermediates fp32
// NOTE: KC/VC are B*H*NC*HD = 2*8*128*64 = 131072 floats EACH.
// (Rounds 0-8 allocated 65536 -> vc tail stomped impb; that was the bug.)
#define OFF_Q    ((size_t)0)
#define OFF_K    ((size_t)4194304)
#define OFF_V    ((size_t)8388608)
#define OFF_O    ((size_t)12582912)
#define OFF_G    ((size_t)16777216)   // B*S*3 = 24576
#define OFF_KC   ((size_t)16801792)   // 131072
#define OFF_VC   ((size_t)16932864)   // 131072
#define OFF_IMPB ((size_t)17063936)   // B*H*NS*NS = 65536
#define OFF_SEL  ((size_t)17129472)   // B*H*NS*TOPK ints = 16384
#define WS_FLOATS ((size_t)17145856)

// -------------------- K1: q/k/v projections (dumb, per-element) ---------------
__global__ __launch_bounds__(256) void k_proj(const float* __restrict__ x,
        const float* __restrict__ Wq, const float* __restrict__ Wk,
        const float* __restrict__ Wv, float* __restrict__ ws)
{
    const int zone = blockIdx.y;  // 0=q 1=k 2=v
    const float* W = (zone == 0) ? Wq : ((zone == 1) ? Wk : Wv);
    float* dst = ws + (size_t)zone * 4194304;
    int idx = blockIdx.x * 256 + threadIdx.x;   // 0 .. 4194303
    int n = idx & 511;
    int m = idx >> 9;                            // 0 .. 8191
    float acc = 0.f;
    const float* xr = x + (size_t)m * DMm;
    for (int kk = 0; kk < DMm; ++kk)
        acc += xr[kk] * W[(size_t)kk * DMm + n];
    int b = m >> 12, s = m & 4095;
    int h = n >> 6, d = n & 63;
    dst[(((size_t)(b * Hh + h)) * Ss + s) * HDd + d] = acc;
}

// -------------------- K2: gate = sigmoid(x @ Wg) (dumb, per-row) --------------
__global__ __launch_bounds__(256) void k_gate(const float* __restrict__ x,
        const float* __restrict__ Wg, float* __restrict__ g)
{
    int row = blockIdx.x * 256 + threadIdx.x;   // 0 .. 8191
    if (row >= Bb * Ss) return;
    const float* xr = x + (size_t)row * DMm;
    float a0 = 0.f, a1 = 0.f, a2 = 0.f;
    for (int d = 0; d < DMm; ++d) {
        float xv = xr[d];
        a0 += xv * Wg[d * 3 + 0];
        a1 += xv * Wg[d * 3 + 1];
        a2 += xv * Wg[d * 3 + 2];
    }
    g[(size_t)row * 3 + 0] = 1.f / (1.f + expf(-a0));
    g[(size_t)row * 3 + 1] = 1.f / (1.f + expf(-a1));
    g[(size_t)row * 3 + 2] = 1.f / (1.f + expf(-a2));
}

// -------------------- K3: mean-pool k,v into chunks ---------------------------
__global__ __launch_bounds__(256) void k_pool(const float* __restrict__ kk,
        const float* __restrict__ vv, float* __restrict__ kc, float* __restrict__ vc)
{
    int idx = blockIdx.x * 256 + threadIdx.x;  // B*H*NC*HD = 131072
    int d = idx & 63;
    int n = (idx >> 6) & 127;
    int bh = idx >> 13;
    const float* kp = kk + ((size_t)bh * Ss + n * CBc) * HDd + d;
    const float* vp = vv + ((size_t)bh * Ss + n * CBc) * HDd + d;
    float sk = 0.f, sv = 0.f;
    for (int t = 0; t < CBc; ++t) { sk += kp[(size_t)t * HDd]; sv += vp[(size_t)t * HDd]; }
    kc[idx] = sk * (1.f / CBc);
    vc[idx] = sv * (1.f / CBc);
}

// -------------------- K3b: zero impb ------------------------------------------
__global__ __launch_bounds__(256) void k_zero(float* __restrict__ p, int n)
{
    int i = blockIdx.x * 256 + threadIdx.x;
    if (i < n) p[i] = 0.f;
}

// -------------------- K4: compressed attention + importance -------------------
__global__ __launch_bounds__(64) void k_cmp(const float* __restrict__ q,
        const float* __restrict__ kc, const float* __restrict__ vc,
        const float* __restrict__ g, float* __restrict__ impb, float* __restrict__ o)
{
    const int s = blockIdx.x;            // 0..4095
    const int bh = blockIdx.y;           // 0..15
    const int b = bh >> 3, h = bh & 7;
    const int l = threadIdx.x;           // 0..63
    __shared__ float qsh[64];
    __shared__ float psh[128];
    __shared__ float red[64];
    __shared__ float m_sh, sum_sh;
    qsh[l] = q[((size_t)bh * Ss + s) * HDd + l];
    __syncthreads();
    const float* kcb = kc + (size_t)bh * NCc * HDd;
    const float* vcb = vc + (size_t)bh * NCc * HDd;
    const int nvis = (s + 1) >> 5;       // visible chunks
    if (nvis > 0) {
        float a0 = 0.f, a1 = 0.f;
        const float* kr0 = kcb + (size_t)l * HDd;
        const float* kr1 = kcb + (size_t)(l + 64) * HDd;
        for (int d = 0; d < 64; ++d) {
            float qd = qsh[d];
            a0 += qd * kr0[d];
            a1 += qd * kr1[d];
        }
        float s0 = (l < nvis) ? a0 * SCALE : NEGF;
        float s1 = (l + 64 < nvis) ? a1 * SCALE : NEGF;
        red[l] = fmaxf(s0, s1);
        __syncthreads();
        if (l == 0) {
            float mm = red[0];
            for (int j = 1; j < 64; ++j) mm = fmaxf(mm, red[j]);
            m_sh = mm;
        }
        __syncthreads();
        float mx = m_sh;
        float p0 = (l < nvis) ? expf(s0 - mx) : 0.f;
        float p1 = (l + 64 < nvis) ? expf(s1 - mx) : 0.f;
        red[l] = p0 + p1;
        __syncthreads();
        if (l == 0) {
            float ss = 0.f;
            for (int j = 0; j < 64; ++j) ss += red[j];
            sum_sh = ss;
        }
        __syncthreads();
        float rinv = 1.f / sum_sh;
        psh[l] = p0 * rinv;
        psh[l + 64] = p1 * rinv;
    } else {
        psh[l] = 0.f;
        psh[l + 64] = 0.f;
    }
    __syncthreads();
    float outl = 0.f;
    for (int n = 0; n < nvis; ++n)
        outl += psh[n] * vcb[(size_t)n * HDd + l];
    float g0 = g[((size_t)(b * Ss + s)) * 3 + 0];
    o[((size_t)(b * Ss + s)) * DMm + h * HDd + l] = g0 * outl;
    float c = psh[2 * l] + psh[2 * l + 1];
    atomicAdd(&impb[((size_t)bh * NSs + (s >> 6)) * NSs + l], c);
}

// -------------------- K5: top-k selection -------------------------------------
__global__ __launch_bounds__(256) void k_topk(const float* __restrict__ impb,
        int* __restrict__ sel)
{
    int row = blockIdx.x * 256 + threadIdx.x;  // B*H*NS = 1024 rows
    if (row >= Bb * Hh * NSs) return;
    int qb = row & 63;
    float v[64];
    for (int j = 0; j < 64; ++j) {
        float t = impb[(size_t)row * 64 + j];
        if (j > qb) t = NEGF;
        if (j == qb) t += 1e9f;
        v[j] = t;
    }
    for (int t = 0; t < TOPKk; ++t) {
        int bi = 0; float bv = v[0];
        for (int j = 1; j < 64; ++j) {
            if (v[j] > bv) { bv = v[j]; bi = j; }
        }
        sel[(size_t)row * TOPKk + t] = bi;
        v[bi] = -3e38f;
    }
}

// -------------------- K6: selected (MODE=0) / window (MODE=1) attention -------
template <int MODE>
__global__ __launch_bounds__(64) void k_attn(const float* __restrict__ q,
        const float* __restrict__ k, const float* __restrict__ v,
        const int* __restrict__ sel, const float* __restrict__ g,
        float* __restrict__ o)
{
    const int s = blockIdx.x;             // 0..4095
    const int bh = blockIdx.y;            // 0..15
    const int b = bh >> 3, h = bh & 7;
    const int l = threadIdx.x;            // 0..63
    const int qb = s >> 6;
    const float* kb_ = k + (size_t)bh * Ss * HDd;
    const float* vb_ = v + (size_t)bh * Ss * HDd;
    __shared__ float qsh[64];
    __shared__ float psh[64];
    __shared__ float red[64];
    __shared__ float m_sh, l_sh, a_sh;
    qsh[l] = q[((size_t)bh * Ss + s) * HDd + l];
    if (l == 0) { m_sh = NEGF; l_sh = 0.f; }
    __syncthreads();
    float outl = 0.f;
    const int NT = (MODE == 0) ? TOPKk : 9;
    for (int t = 0; t < NT; ++t) {
        int kbi;
        if (MODE == 0) {
            kbi = sel[((size_t)bh * NSs + qb) * TOPKk + t];
        } else {
            kbi = qb - 8 + t;
            if (kbi < 0) continue;       // block-uniform
        }
        const int kbase = kbi * 64;
        const int kpos = kbase + l;
        float sc = 0.f;
        const float* kr = kb_ + (size_t)(kbase + l) * HDd;
        for (int d = 0; d < 64; ++d) sc += qsh[d] * kr[d];
        bool valid = (kpos <= s);
        if (MODE == 1) valid = valid && (kpos > s - WINSZ);
        float scv = valid ? sc * SCALE : NEGF;
        red[l] = scv;
        __syncthreads();
        if (l == 0) {
            float mx = red[0];
            for (int j = 1; j < 64; ++j) mx = fmaxf(mx, red[j]);
            float mold = m_sh;
            float mnew = fmaxf(mold, mx);
            a_sh = expf(mold - mnew);
            m_sh = mnew;
        }
        __syncthreads();
        float mnew = m_sh;
        float alpha = a_sh;
        float p = valid ? expf(scv - mnew) : 0.f;
        psh[l] = p;
        red[l] = p;
        __syncthreads();
        if (l == 0) {
            float rs = 0.f;
            for (int j = 0; j < 64; ++j) rs += red[j];
            l_sh = l_sh * alpha + rs;
        }
        float acc = outl * alpha;
        const float* vr = vb_ + (size_t)kbase * HDd + l;
        for (int j = 0; j < 64; ++j)
            acc += psh[j] * vr[(size_t)j * HDd];
        outl = acc;
        __syncthreads();
    }
    float lsum = l_sh;
    float gv = g[((size_t)(b * Ss + s)) * 3 + ((MODE == 0) ? 1 : 2)];
    o[((size_t)(b * Ss + s)) * DMm + h * HDd + l] += (outl / lsum) * gv;
}

// -------------------- K7: y = o @ Wo (dumb, per-element, fp32 out) ------------
__global__ __launch_bounds__(256) void k_outproj(const float* __restrict__ o,
        const float* __restrict__ Wo, float* __restrict__ y)
{
    int idx = blockIdx.x * 256 + threadIdx.x;   // 0 .. 4194303
    int n = idx & 511;
    int m = idx >> 9;                            // 0 .. 8191
    float acc = 0.f;
    const float* orow = o + (size_t)m * DMm;
    for (int kk = 0; kk < DMm; ++kk)
        acc += orow[kk] * Wo[(size_t)kk * DMm + n];
    y[(size_t)m * DMm + n] = acc;
}

// -------------------- constant emitter (host-side contract checks) ------------
__global__ __launch_bounds__(256) void k_const(float* __restrict__ y, float val)
{
    int i = blockIdx.x * 256 + threadIdx.x;
    y[i] = val;
}

// -------------------- launch --------------------------------------------------
extern "C" void kernel_launch(void* const* d_in, const int* in_sizes, int n_in,
                              void* d_out, int out_size, void* d_ws, size_t ws_size,
                              hipStream_t stream) {
    float* y = (float*)d_out;
    if (n_in != 6) {
        k_const<<<dim3(16384), 256, 0, stream>>>(y, 88888.f);
        return;
    }
    if (in_sizes[0] != 4194304 || in_sizes[1] != 262144 || in_sizes[2] != 262144 ||
        in_sizes[3] != 262144 || in_sizes[4] != 262144 || in_sizes[5] != 1536) {
        k_const<<<dim3(16384), 256, 0, stream>>>(y, 77777.f);
        return;
    }
    if (ws_size < WS_FLOATS * sizeof(float)) {
        k_const<<<dim3(16384), 256, 0, stream>>>(y, 66666.f);
        return;
    }

    const float* x  = (const float*)d_in[0];
    const float* Wq = (const float*)d_in[1];
    const float* Wk = (const float*)d_in[2];
    const float* Wv = (const float*)d_in[3];
    const float* Wo = (const float*)d_in[4];
    const float* Wg = (const float*)d_in[5];
    float* ws = (float*)d_ws;

    float* qw   = ws + OFF_Q;
    float* kw   = ws + OFF_K;
    float* vw   = ws + OFF_V;
    float* ow   = ws + OFF_O;
    float* gw   = ws + OFF_G;
    float* kcw  = ws + OFF_KC;
    float* vcw  = ws + OFF_VC;
    float* impw = ws + OFF_IMPB;
    int*   selw = (int*)(ws + OFF_SEL);

    k_proj<<<dim3(16384, 3), 256, 0, stream>>>(x, Wq, Wk, Wv, ws);
    k_gate<<<dim3(32), 256, 0, stream>>>(x, Wg, gw);
    k_pool<<<dim3(512), 256, 0, stream>>>(kw, vw, kcw, vcw);
    k_zero<<<dim3(256), 256, 0, stream>>>(impw, Bb * Hh * NSs * NSs);
    k_cmp<<<dim3(4096, 16), 64, 0, stream>>>(qw, kcw, vcw, gw, impw, ow);
    k_topk<<<dim3(4), 256, 0, stream>>>(impw, selw);
    k_attn<0><<<dim3(4096, 16), 64, 0, stream>>>(qw, kw, vw, selw, gw, ow);
    k_attn<1><<<dim3(4096, 16), 64, 0, stream>>>(qw, kw, vw, selw, gw, ow);
    k_outproj<<<dim3(16384), 256, 0, stream>>>(ow, Wo, y);
}

// Round 10
// 2363.781 us; speedup vs baseline: 2.4218x; 2.4218x over previous
//
#include <hip/hip_runtime.h>

// Problem constants
#define Hh    8
#define DMm   512
#define HDd   64
#define CBc   32
#define SBs   64
#define WINSZ 512
#define TOPKk 16
#define NEGF  (-1e30f)
#define Bb    2
#define Ss    4096
#define NCc   128   // S/CB
#define NSs   64    // S/SB
#define SCALE 0.125f

// Workspace layout (float offsets) — intermediates fp32
// KC/VC are B*H*NC*HD = 131072 floats EACH (rounds 0-8 under-allocated -> stomp).
#define OFF_Q    ((size_t)0)
#define OFF_K    ((size_t)4194304)
#define OFF_V    ((size_t)8388608)
#define OFF_O    ((size_t)12582912)
#define OFF_G    ((size_t)16777216)   // B*S*3 = 24576
#define OFF_KC   ((size_t)16801792)   // 131072
#define OFF_VC   ((size_t)16932864)   // 131072
#define OFF_IMPB ((size_t)17063936)   // B*H*NS*NS = 65536
#define OFF_SEL  ((size_t)17129472)   // B*H*NS*TOPK ints = 16384
#define WS_FLOATS ((size_t)17145856)

// -------------------- K1: q/k/v projections (tiled 64x64 fp32 GEMM) -----------
__global__ __launch_bounds__(256) void k_proj(const float* __restrict__ x,
        const float* __restrict__ Wq, const float* __restrict__ Wk,
        const float* __restrict__ Wv, float* __restrict__ ws)
{
    const int zone = blockIdx.z;  // 0=q 1=k 2=v
    const float* W = (zone == 0) ? Wq : ((zone == 1) ? Wk : Wv);
    float* dst = ws + (size_t)zone * 4194304;
    const int m0 = blockIdx.x * 64;
    const int n0 = blockIdx.y * 64;
    __shared__ float As[16][68];  // [k][m]
    __shared__ float Bs[16][68];  // [k][n]
    const int tid = threadIdx.x;
    const int tx = tid & 15, ty = tid >> 4;
    float acc[4][4] = {};
    for (int k0 = 0; k0 < DMm; k0 += 16) {
        {
            int r = tid >> 2;
            int kq = (tid & 3) * 4;
            float4 t4 = *(const float4*)(x + (size_t)(m0 + r) * DMm + k0 + kq);
            As[kq + 0][r] = t4.x;
            As[kq + 1][r] = t4.y;
            As[kq + 2][r] = t4.z;
            As[kq + 3][r] = t4.w;
        }
        {
            int kk = tid >> 4;
            int nq = (tid & 15) * 4;
            float4 t4 = *(const float4*)(W + (size_t)(k0 + kk) * DMm + n0 + nq);
            Bs[kk][nq + 0] = t4.x;
            Bs[kk][nq + 1] = t4.y;
            Bs[kk][nq + 2] = t4.z;
            Bs[kk][nq + 3] = t4.w;
        }
        __syncthreads();
#pragma unroll
        for (int kk = 0; kk < 16; ++kk) {
            float4 av = *(const float4*)&As[kk][ty * 4];
            float4 bv = *(const float4*)&Bs[kk][tx * 4];
            acc[0][0] += av.x * bv.x; acc[0][1] += av.x * bv.y; acc[0][2] += av.x * bv.z; acc[0][3] += av.x * bv.w;
            acc[1][0] += av.y * bv.x; acc[1][1] += av.y * bv.y; acc[1][2] += av.y * bv.z; acc[1][3] += av.y * bv.w;
            acc[2][0] += av.z * bv.x; acc[2][1] += av.z * bv.y; acc[2][2] += av.z * bv.z; acc[2][3] += av.z * bv.w;
            acc[3][0] += av.w * bv.x; acc[3][1] += av.w * bv.y; acc[3][2] += av.w * bv.z; acc[3][3] += av.w * bv.w;
        }
        __syncthreads();
    }
    const int h = n0 >> 6;   // n0 is a multiple of 64 -> tile maps to exactly one head
#pragma unroll
    for (int i = 0; i < 4; ++i) {
        int m = m0 + ty * 4 + i;
        int b = m >> 12;
        int s = m & 4095;
#pragma unroll
        for (int j = 0; j < 4; ++j) {
            int d = tx * 4 + j;
            dst[(((size_t)(b * Hh + h)) * Ss + s) * HDd + d] = acc[i][j];
        }
    }
}

// -------------------- K2: gate = sigmoid(x @ Wg) (dumb, per-row) --------------
__global__ __launch_bounds__(256) void k_gate(const float* __restrict__ x,
        const float* __restrict__ Wg, float* __restrict__ g)
{
    int row = blockIdx.x * 256 + threadIdx.x;   // 0 .. 8191
    if (row >= Bb * Ss) return;
    const float* xr = x + (size_t)row * DMm;
    float a0 = 0.f, a1 = 0.f, a2 = 0.f;
    for (int d = 0; d < DMm; ++d) {
        float xv = xr[d];
        a0 += xv * Wg[d * 3 + 0];
        a1 += xv * Wg[d * 3 + 1];
        a2 += xv * Wg[d * 3 + 2];
    }
    g[(size_t)row * 3 + 0] = 1.f / (1.f + expf(-a0));
    g[(size_t)row * 3 + 1] = 1.f / (1.f + expf(-a1));
    g[(size_t)row * 3 + 2] = 1.f / (1.f + expf(-a2));
}

// -------------------- K3: mean-pool k,v into chunks ---------------------------
__global__ __launch_bounds__(256) void k_pool(const float* __restrict__ kk,
        const float* __restrict__ vv, float* __restrict__ kc, float* __restrict__ vc)
{
    int idx = blockIdx.x * 256 + threadIdx.x;  // B*H*NC*HD = 131072
    int d = idx & 63;
    int n = (idx >> 6) & 127;
    int bh = idx >> 13;
    const float* kp = kk + ((size_t)bh * Ss + n * CBc) * HDd + d;
    const float* vp = vv + ((size_t)bh * Ss + n * CBc) * HDd + d;
    float sk = 0.f, sv = 0.f;
    for (int t = 0; t < CBc; ++t) { sk += kp[(size_t)t * HDd]; sv += vp[(size_t)t * HDd]; }
    kc[idx] = sk * (1.f / CBc);
    vc[idx] = sv * (1.f / CBc);
}

// -------------------- K3b: zero impb ------------------------------------------
__global__ __launch_bounds__(256) void k_zero(float* __restrict__ p, int n)
{
    int i = blockIdx.x * 256 + threadIdx.x;
    if (i < n) p[i] = 0.f;
}

// -------------------- K4: compressed attention + importance (known-correct) ---
__global__ __launch_bounds__(64) void k_cmp(const float* __restrict__ q,
        const float* __restrict__ kc, const float* __restrict__ vc,
        const float* __restrict__ g, float* __restrict__ impb, float* __restrict__ o)
{
    const int s = blockIdx.x;            // 0..4095
    const int bh = blockIdx.y;           // 0..15
    const int b = bh >> 3, h = bh & 7;
    const int l = threadIdx.x;           // 0..63
    __shared__ float qsh[64];
    __shared__ float psh[128];
    __shared__ float red[64];
    __shared__ float m_sh, sum_sh;
    qsh[l] = q[((size_t)bh * Ss + s) * HDd + l];
    __syncthreads();
    const float* kcb = kc + (size_t)bh * NCc * HDd;
    const float* vcb = vc + (size_t)bh * NCc * HDd;
    const int nvis = (s + 1) >> 5;       // visible chunks
    if (nvis > 0) {
        float a0 = 0.f, a1 = 0.f;
        const float* kr0 = kcb + (size_t)l * HDd;
        const float* kr1 = kcb + (size_t)(l + 64) * HDd;
        for (int d = 0; d < 64; ++d) {
            float qd = qsh[d];
            a0 += qd * kr0[d];
            a1 += qd * kr1[d];
        }
        float s0 = (l < nvis) ? a0 * SCALE : NEGF;
        float s1 = (l + 64 < nvis) ? a1 * SCALE : NEGF;
        red[l] = fmaxf(s0, s1);
        __syncthreads();
        if (l == 0) {
            float mm = red[0];
            for (int j = 1; j < 64; ++j) mm = fmaxf(mm, red[j]);
            m_sh = mm;
        }
        __syncthreads();
        float mx = m_sh;
        float p0 = (l < nvis) ? expf(s0 - mx) : 0.f;
        float p1 = (l + 64 < nvis) ? expf(s1 - mx) : 0.f;
        red[l] = p0 + p1;
        __syncthreads();
        if (l == 0) {
            float ss = 0.f;
            for (int j = 0; j < 64; ++j) ss += red[j];
            sum_sh = ss;
        }
        __syncthreads();
        float rinv = 1.f / sum_sh;
        psh[l] = p0 * rinv;
        psh[l + 64] = p1 * rinv;
    } else {
        psh[l] = 0.f;
        psh[l + 64] = 0.f;
    }
    __syncthreads();
    float outl = 0.f;
    for (int n = 0; n < nvis; ++n)
        outl += psh[n] * vcb[(size_t)n * HDd + l];
    float g0 = g[((size_t)(b * Ss + s)) * 3 + 0];
    o[((size_t)(b * Ss + s)) * DMm + h * HDd + l] = g0 * outl;
    float c = psh[2 * l] + psh[2 * l + 1];
    atomicAdd(&impb[((size_t)bh * NSs + (s >> 6)) * NSs + l], c);
}

// -------------------- K5: top-k selection -------------------------------------
__global__ __launch_bounds__(256) void k_topk(const float* __restrict__ impb,
        int* __restrict__ sel)
{
    int row = blockIdx.x * 256 + threadIdx.x;  // B*H*NS = 1024 rows
    if (row >= Bb * Hh * NSs) return;
    int qb = row & 63;
    float v[64];
    for (int j = 0; j < 64; ++j) {
        float t = impb[(size_t)row * 64 + j];
        if (j > qb) t = NEGF;
        if (j == qb) t += 1e9f;
        v[j] = t;
    }
    for (int t = 0; t < TOPKk; ++t) {
        int bi = 0; float bv = v[0];
        for (int j = 1; j < 64; ++j) {
            if (v[j] > bv) { bv = v[j]; bi = j; }
        }
        sel[(size_t)row * TOPKk + t] = bi;
        v[bi] = -3e38f;
    }
}

// -------------------- K6: tiled selected (MODE=0) / window (MODE=1) attention -
// 32 queries x 256 threads per block; K/V staged in LDS (coalesced, <=2-way
// bank aliasing everywhere = free); online softmax rows on wave 0.
template <int MODE>
__global__ __launch_bounds__(256) void k_attn(const float* __restrict__ q,
        const float* __restrict__ k, const float* __restrict__ v,
        const int* __restrict__ sel, const float* __restrict__ g,
        float* __restrict__ o)
{
    const int qt = blockIdx.x;    // 0..127 : 32-query tiles
    const int bh = blockIdx.y;
    const int b = bh >> 3, h = bh & 7;
    const int qb = qt >> 1;       // 64-query selection/window block index
    const int q0 = qt * 32;
    const int tid = threadIdx.x;
    __shared__ float qs[32][64];
    __shared__ float kT[64][65];  // [d][kk] padded
    __shared__ float vs[64][64];  // [kk][d]
    __shared__ float sc[32][65];  // scores / probs, padded
    __shared__ float mrow[32], lrow[32], arow[32];
    for (int i = tid; i < 32 * 64; i += 256) {
        int r = i >> 6, d = i & 63;
        qs[r][d] = q[((size_t)bh * Ss + q0 + r) * HDd + d];
    }
    if (tid < 32) { mrow[tid] = NEGF; lrow[tid] = 0.f; }
    float outr[8] = {0.f, 0.f, 0.f, 0.f, 0.f, 0.f, 0.f, 0.f};
    const int dl = tid & 63;
    const int qg = tid >> 6;
    __syncthreads();
    const int NT = (MODE == 0) ? TOPKk : 9;
    for (int t = 0; t < NT; ++t) {
        int kb;
        if (MODE == 0) kb = sel[((size_t)bh * NSs + qb) * TOPKk + t];
        else { kb = qb - 8 + t; if (kb < 0) continue; }   // block-uniform
        const int kbase = kb * 64;
        for (int i = tid; i < 64 * 64; i += 256) {
            int r = i >> 6, d = i & 63;
            kT[d][r] = k[((size_t)bh * Ss + kbase + r) * HDd + d];
            vs[r][d] = v[((size_t)bh * Ss + kbase + r) * HDd + d];
        }
        __syncthreads();
        // scores: thread (qg,kk) covers 8 rows
        {
            int kk = tid & 63;
            int kpos = kbase + kk;
#pragma unroll
            for (int qi = 0; qi < 8; ++qi) {
                int qq = qg + 4 * qi;
                int qpos = q0 + qq;
                float acc = 0.f;
#pragma unroll
                for (int d = 0; d < 64; ++d)
                    acc += qs[qq][d] * kT[d][kk];
                bool valid = (kpos <= qpos);
                if (MODE == 1) valid = valid && (kpos > qpos - WINSZ);
                sc[qq][kk] = valid ? acc * SCALE : NEGF;
            }
        }
        __syncthreads();
        // online softmax per row (wave 0, one lane per row)
        if (tid < 32) {
            int qq = tid;
            float mx = NEGF;
            for (int kk = 0; kk < 64; ++kk) mx = fmaxf(mx, sc[qq][kk]);
            float mold = mrow[qq];
            float mnew = fmaxf(mold, mx);
            float alpha, rs = 0.f;
            if (mnew <= NEGF * 0.5f) {    // row still entirely masked
                alpha = 1.f;
                for (int kk = 0; kk < 64; ++kk) sc[qq][kk] = 0.f;
            } else {
                alpha = expf(mold - mnew);   // mold=NEG -> 0
                for (int kk = 0; kk < 64; ++kk) {
                    float sv = sc[qq][kk];
                    float p = (sv <= NEGF * 0.5f) ? 0.f : expf(sv - mnew);
                    sc[qq][kk] = p;
                    rs += p;
                }
            }
            lrow[qq] = lrow[qq] * alpha + rs;
            mrow[qq] = mnew;
            arow[qq] = alpha;
        }
        __syncthreads();
        // PV accumulate into registers
#pragma unroll
        for (int qi = 0; qi < 8; ++qi) {
            int qq = qg + 4 * qi;
            float a = arow[qq];
            float acc = outr[qi] * a;
#pragma unroll
            for (int kk = 0; kk < 64; ++kk)
                acc += sc[qq][kk] * vs[kk][dl];
            outr[qi] = acc;
        }
        __syncthreads();   // protect kT/vs/sc before next tile
    }
    // epilogue: o += g * out / l   (lsum >= 1: self-key always valid)
#pragma unroll
    for (int qi = 0; qi < 8; ++qi) {
        int qq = qg + 4 * qi;
        int s = q0 + qq;
        float li = lrow[qq];
        float gv = g[((size_t)(b * Ss + s)) * 3 + ((MODE == 0) ? 1 : 2)];
        size_t oi = ((size_t)(b * Ss + s)) * DMm + h * HDd + dl;
        o[oi] += (outr[qi] / li) * gv;
    }
}

// -------------------- K7: y = o @ Wo (tiled 64x64 fp32 GEMM) ------------------
__global__ __launch_bounds__(256) void k_outproj(const float* __restrict__ o,
        const float* __restrict__ Wo, float* __restrict__ y)
{
    const int m0 = blockIdx.x * 64;
    const int n0 = blockIdx.y * 64;
    __shared__ float As[16][68];
    __shared__ float Bs[16][68];
    const int tid = threadIdx.x;
    const int tx = tid & 15, ty = tid >> 4;
    float acc[4][4] = {};
    for (int k0 = 0; k0 < DMm; k0 += 16) {
        {
            int r = tid >> 2;
            int kq = (tid & 3) * 4;
            float4 t4 = *(const float4*)(o + (size_t)(m0 + r) * DMm + k0 + kq);
            As[kq + 0][r] = t4.x;
            As[kq + 1][r] = t4.y;
            As[kq + 2][r] = t4.z;
            As[kq + 3][r] = t4.w;
        }
        {
            int kk = tid >> 4;
            int nq = (tid & 15) * 4;
            float4 t4 = *(const float4*)(Wo + (size_t)(k0 + kk) * DMm + n0 + nq);
            Bs[kk][nq + 0] = t4.x;
            Bs[kk][nq + 1] = t4.y;
            Bs[kk][nq + 2] = t4.z;
            Bs[kk][nq + 3] = t4.w;
        }
        __syncthreads();
#pragma unroll
        for (int kk = 0; kk < 16; ++kk) {
            float4 av = *(const float4*)&As[kk][ty * 4];
            float4 bv = *(const float4*)&Bs[kk][tx * 4];
            acc[0][0] += av.x * bv.x; acc[0][1] += av.x * bv.y; acc[0][2] += av.x * bv.z; acc[0][3] += av.x * bv.w;
            acc[1][0] += av.y * bv.x; acc[1][1] += av.y * bv.y; acc[1][2] += av.y * bv.z; acc[1][3] += av.y * bv.w;
            acc[2][0] += av.z * bv.x; acc[2][1] += av.z * bv.y; acc[2][2] += av.z * bv.z; acc[2][3] += av.z * bv.w;
            acc[3][0] += av.w * bv.x; acc[3][1] += av.w * bv.y; acc[3][2] += av.w * bv.z; acc[3][3] += av.w * bv.w;
        }
        __syncthreads();
    }
#pragma unroll
    for (int i = 0; i < 4; ++i) {
        int m = m0 + ty * 4 + i;
#pragma unroll
        for (int j = 0; j < 4; ++j) {
            int n = n0 + tx * 4 + j;
            y[(size_t)m * DMm + n] = acc[i][j];
        }
    }
}

// -------------------- constant emitter (host-side contract checks) ------------
__global__ __launch_bounds__(256) void k_const(float* __restrict__ y, float val)
{
    int i = blockIdx.x * 256 + threadIdx.x;
    y[i] = val;
}

// -------------------- launch --------------------------------------------------
extern "C" void kernel_launch(void* const* d_in, const int* in_sizes, int n_in,
                              void* d_out, int out_size, void* d_ws, size_t ws_size,
                              hipStream_t stream) {
    float* y = (float*)d_out;
    if (n_in != 6) {
        k_const<<<dim3(16384), 256, 0, stream>>>(y, 88888.f);
        return;
    }
    if (in_sizes[0] != 4194304 || in_sizes[1] != 262144 || in_sizes[2] != 262144 ||
        in_sizes[3] != 262144 || in_sizes[4] != 262144 || in_sizes[5] != 1536) {
        k_const<<<dim3(16384), 256, 0, stream>>>(y, 77777.f);
        return;
    }
    if (ws_size < WS_FLOATS * sizeof(float)) {
        k_const<<<dim3(16384), 256, 0, stream>>>(y, 66666.f);
        return;
    }

    const float* x  = (const float*)d_in[0];
    const float* Wq = (const float*)d_in[1];
    const float* Wk = (const float*)d_in[2];
    const float* Wv = (const float*)d_in[3];
    const float* Wo = (const float*)d_in[4];
    const float* Wg = (const float*)d_in[5];
    float* ws = (float*)d_ws;

    float* qw   = ws + OFF_Q;
    float* kw   = ws + OFF_K;
    float* vw   = ws + OFF_V;
    float* ow   = ws + OFF_O;
    float* gw   = ws + OFF_G;
    float* kcw  = ws + OFF_KC;
    float* vcw  = ws + OFF_VC;
    float* impw = ws + OFF_IMPB;
    int*   selw = (int*)(ws + OFF_SEL);

    k_proj<<<dim3(128, 8, 3), 256, 0, stream>>>(x, Wq, Wk, Wv, ws);
    k_gate<<<dim3(32), 256, 0, stream>>>(x, Wg, gw);
    k_pool<<<dim3(512), 256, 0, stream>>>(kw, vw, kcw, vcw);
    k_zero<<<dim3(256), 256, 0, stream>>>(impw, Bb * Hh * NSs * NSs);
    k_cmp<<<dim3(4096, 16), 64, 0, stream>>>(qw, kcw, vcw, gw, impw, ow);
    k_topk<<<dim3(4), 256, 0, stream>>>(impw, selw);
    k_attn<0><<<dim3(128, 16), 256, 0, stream>>>(qw, kw, vw, selw, gw, ow);
    k_attn<1><<<dim3(128, 16), 256, 0, stream>>>(qw, kw, vw, selw, gw, ow);
    k_outproj<<<dim3(128, 8), 256, 0, stream>>>(ow, Wo, y);
}

// Round 11
// 1471.269 us; speedup vs baseline: 3.8909x; 1.6066x over previous
//
#include <hip/hip_runtime.h>

// Problem constants
#define Hh    8
#define DMm   512
#define HDd   64
#define CBc   32
#define SBs   64
#define WINSZ 512
#define TOPKk 16
#define NEGF  (-1e30f)
#define Bb    2
#define Ss    4096
#define NCc   128   // S/CB
#define NSs   64    // S/SB
#define SCALE 0.125f

// Workspace layout (float offsets) — intermediates fp32
// KC/VC are B*H*NC*HD = 131072 floats EACH (rounds 0-8 under-allocated -> stomp).
#define OFF_Q    ((size_t)0)
#define OFF_K    ((size_t)4194304)
#define OFF_V    ((size_t)8388608)
#define OFF_O    ((size_t)12582912)
#define OFF_G    ((size_t)16777216)   // B*S*3 = 24576
#define OFF_KC   ((size_t)16801792)   // 131072
#define OFF_VC   ((size_t)16932864)   // 131072
#define OFF_IMPB ((size_t)17063936)   // B*H*NS*NS = 65536
#define OFF_SEL  ((size_t)17129472)   // B*H*NS*TOPK ints = 16384
#define WS_FLOATS ((size_t)17145856)

// -------------------- K1: q/k/v projections (tiled 64x64 fp32 GEMM) -----------
__global__ __launch_bounds__(256) void k_proj(const float* __restrict__ x,
        const float* __restrict__ Wq, const float* __restrict__ Wk,
        const float* __restrict__ Wv, float* __restrict__ ws)
{
    const int zone = blockIdx.z;  // 0=q 1=k 2=v
    const float* W = (zone == 0) ? Wq : ((zone == 1) ? Wk : Wv);
    float* dst = ws + (size_t)zone * 4194304;
    const int m0 = blockIdx.x * 64;
    const int n0 = blockIdx.y * 64;
    __shared__ float As[16][68];  // [k][m]
    __shared__ float Bs[16][68];  // [k][n]
    const int tid = threadIdx.x;
    const int tx = tid & 15, ty = tid >> 4;
    float acc[4][4] = {};
    for (int k0 = 0; k0 < DMm; k0 += 16) {
        {
            int r = tid >> 2;
            int kq = (tid & 3) * 4;
            float4 t4 = *(const float4*)(x + (size_t)(m0 + r) * DMm + k0 + kq);
            As[kq + 0][r] = t4.x;
            As[kq + 1][r] = t4.y;
            As[kq + 2][r] = t4.z;
            As[kq + 3][r] = t4.w;
        }
        {
            int kk = tid >> 4;
            int nq = (tid & 15) * 4;
            float4 t4 = *(const float4*)(W + (size_t)(k0 + kk) * DMm + n0 + nq);
            Bs[kk][nq + 0] = t4.x;
            Bs[kk][nq + 1] = t4.y;
            Bs[kk][nq + 2] = t4.z;
            Bs[kk][nq + 3] = t4.w;
        }
        __syncthreads();
#pragma unroll
        for (int kk = 0; kk < 16; ++kk) {
            float4 av = *(const float4*)&As[kk][ty * 4];
            float4 bv = *(const float4*)&Bs[kk][tx * 4];
            acc[0][0] += av.x * bv.x; acc[0][1] += av.x * bv.y; acc[0][2] += av.x * bv.z; acc[0][3] += av.x * bv.w;
            acc[1][0] += av.y * bv.x; acc[1][1] += av.y * bv.y; acc[1][2] += av.y * bv.z; acc[1][3] += av.y * bv.w;
            acc[2][0] += av.z * bv.x; acc[2][1] += av.z * bv.y; acc[2][2] += av.z * bv.z; acc[2][3] += av.z * bv.w;
            acc[3][0] += av.w * bv.x; acc[3][1] += av.w * bv.y; acc[3][2] += av.w * bv.z; acc[3][3] += av.w * bv.w;
        }
        __syncthreads();
    }
    const int h = n0 >> 6;
#pragma unroll
    for (int i = 0; i < 4; ++i) {
        int m = m0 + ty * 4 + i;
        int b = m >> 12;
        int s = m & 4095;
#pragma unroll
        for (int j = 0; j < 4; ++j) {
            int d = tx * 4 + j;
            dst[(((size_t)(b * Hh + h)) * Ss + s) * HDd + d] = acc[i][j];
        }
    }
}

// -------------------- K2: gate = sigmoid(x @ Wg) ------------------------------
__global__ __launch_bounds__(256) void k_gate(const float* __restrict__ x,
        const float* __restrict__ Wg, float* __restrict__ g)
{
    int row = blockIdx.x * 256 + threadIdx.x;   // 0 .. 8191
    if (row >= Bb * Ss) return;
    const float* xr = x + (size_t)row * DMm;
    float a0 = 0.f, a1 = 0.f, a2 = 0.f;
    for (int d = 0; d < DMm; ++d) {
        float xv = xr[d];
        a0 += xv * Wg[d * 3 + 0];
        a1 += xv * Wg[d * 3 + 1];
        a2 += xv * Wg[d * 3 + 2];
    }
    g[(size_t)row * 3 + 0] = 1.f / (1.f + expf(-a0));
    g[(size_t)row * 3 + 1] = 1.f / (1.f + expf(-a1));
    g[(size_t)row * 3 + 2] = 1.f / (1.f + expf(-a2));
}

// -------------------- K3: mean-pool k,v into chunks ---------------------------
__global__ __launch_bounds__(256) void k_pool(const float* __restrict__ kk,
        const float* __restrict__ vv, float* __restrict__ kc, float* __restrict__ vc)
{
    int idx = blockIdx.x * 256 + threadIdx.x;  // B*H*NC*HD = 131072
    int d = idx & 63;
    int n = (idx >> 6) & 127;
    int bh = idx >> 13;
    const float* kp = kk + ((size_t)bh * Ss + n * CBc) * HDd + d;
    const float* vp = vv + ((size_t)bh * Ss + n * CBc) * HDd + d;
    float sk = 0.f, sv = 0.f;
    for (int t = 0; t < CBc; ++t) { sk += kp[(size_t)t * HDd]; sv += vp[(size_t)t * HDd]; }
    kc[idx] = sk * (1.f / CBc);
    vc[idx] = sv * (1.f / CBc);
}

// -------------------- K3b: zero impb ------------------------------------------
__global__ __launch_bounds__(256) void k_zero(float* __restrict__ p, int n)
{
    int i = blockIdx.x * 256 + threadIdx.x;
    if (i < n) p[i] = 0.f;
}

// -------------------- K4: compressed attention + importance (known-correct) ---
__global__ __launch_bounds__(64) void k_cmp(const float* __restrict__ q,
        const float* __restrict__ kc, const float* __restrict__ vc,
        const float* __restrict__ g, float* __restrict__ impb, float* __restrict__ o)
{
    const int s = blockIdx.x;            // 0..4095
    const int bh = blockIdx.y;           // 0..15
    const int b = bh >> 3, h = bh & 7;
    const int l = threadIdx.x;           // 0..63
    __shared__ float qsh[64];
    __shared__ float psh[128];
    __shared__ float red[64];
    __shared__ float m_sh, sum_sh;
    qsh[l] = q[((size_t)bh * Ss + s) * HDd + l];
    __syncthreads();
    const float* kcb = kc + (size_t)bh * NCc * HDd;
    const float* vcb = vc + (size_t)bh * NCc * HDd;
    const int nvis = (s + 1) >> 5;       // visible chunks
    if (nvis > 0) {
        float a0 = 0.f, a1 = 0.f;
        const float* kr0 = kcb + (size_t)l * HDd;
        const float* kr1 = kcb + (size_t)(l + 64) * HDd;
        for (int d = 0; d < 64; ++d) {
            float qd = qsh[d];
            a0 += qd * kr0[d];
            a1 += qd * kr1[d];
        }
        float s0 = (l < nvis) ? a0 * SCALE : NEGF;
        float s1 = (l + 64 < nvis) ? a1 * SCALE : NEGF;
        red[l] = fmaxf(s0, s1);
        __syncthreads();
        if (l == 0) {
            float mm = red[0];
            for (int j = 1; j < 64; ++j) mm = fmaxf(mm, red[j]);
            m_sh = mm;
        }
        __syncthreads();
        float mx = m_sh;
        float p0 = (l < nvis) ? expf(s0 - mx) : 0.f;
        float p1 = (l + 64 < nvis) ? expf(s1 - mx) : 0.f;
        red[l] = p0 + p1;
        __syncthreads();
        if (l == 0) {
            float ss = 0.f;
            for (int j = 0; j < 64; ++j) ss += red[j];
            sum_sh = ss;
        }
        __syncthreads();
        float rinv = 1.f / sum_sh;
        psh[l] = p0 * rinv;
        psh[l + 64] = p1 * rinv;
    } else {
        psh[l] = 0.f;
        psh[l + 64] = 0.f;
    }
    __syncthreads();
    float outl = 0.f;
    for (int n = 0; n < nvis; ++n)
        outl += psh[n] * vcb[(size_t)n * HDd + l];
    float g0 = g[((size_t)(b * Ss + s)) * 3 + 0];
    o[((size_t)(b * Ss + s)) * DMm + h * HDd + l] = g0 * outl;
    float c = psh[2 * l] + psh[2 * l + 1];
    atomicAdd(&impb[((size_t)bh * NSs + (s >> 6)) * NSs + l], c);
}

// -------------------- K5: top-k selection -------------------------------------
__global__ __launch_bounds__(256) void k_topk(const float* __restrict__ impb,
        int* __restrict__ sel)
{
    int row = blockIdx.x * 256 + threadIdx.x;  // B*H*NS = 1024 rows
    if (row >= Bb * Hh * NSs) return;
    int qb = row & 63;
    float v[64];
    for (int j = 0; j < 64; ++j) {
        float t = impb[(size_t)row * 64 + j];
        if (j > qb) t = NEGF;
        if (j == qb) t += 1e9f;
        v[j] = t;
    }
    for (int t = 0; t < TOPKk; ++t) {
        int bi = 0; float bv = v[0];
        for (int j = 1; j < 64; ++j) {
            if (v[j] > bv) { bv = v[j]; bi = j; }
        }
        sel[(size_t)row * TOPKk + t] = bi;
        v[bi] = -3e38f;
    }
}

// -------------------- K6: attention, 64-query tiles, register-blocked ---------
// MODE 0 = selected (16 tiles from sel), MODE 1 = window (9 tiles qb-8..qb).
// 256 threads; K and V share one LDS buffer (K dead after scores);
// softmax parallel: 4 lanes per row via __shfl_xor(1,2).
template <int MODE>
__global__ __launch_bounds__(256) void k_attn(const float* __restrict__ q,
        const float* __restrict__ k, const float* __restrict__ v,
        const int* __restrict__ sel, const float* __restrict__ g,
        float* __restrict__ o)
{
    const int qb = blockIdx.x;    // 0..63
    const int bh = blockIdx.y;
    const int b = bh >> 3, h = bh & 7;
    const int q0 = qb * 64;
    const int tid = threadIdx.x;
    const int qg = tid >> 6;      // 0..3
    const int kl = tid & 63;      // key col in scores / d col in PV
    __shared__ float qs[64 * 64];      // [row][d], stride 64
    __shared__ float kv[64 * 65];      // K as [d][kk] then V as [kk][d], stride 65
    __shared__ float sc[64 * 68];      // scores/probs [row][kk], stride 68 (16B-align)
    __shared__ float mrow[64], lrow[64], arow[64];
    for (int i = tid; i < 64 * 64; i += 256)
        qs[i] = q[((size_t)bh * Ss + q0) * HDd + i];
    if (tid < 64) { mrow[tid] = NEGF; lrow[tid] = 0.f; }
    float outr[16];
#pragma unroll
    for (int i = 0; i < 16; ++i) outr[i] = 0.f;
    __syncthreads();
    const int NT = (MODE == 0) ? TOPKk : 9;
    for (int t = 0; t < NT; ++t) {
        int kb;
        if (MODE == 0) kb = sel[((size_t)bh * NSs + qb) * TOPKk + t];
        else { kb = qb - 8 + t; if (kb < 0) continue; }   // block-uniform
        const int kbase = kb * 64;
        // stage K transposed: kv[d*65 + r]
        for (int i = tid; i < 64 * 64; i += 256) {
            int r = i >> 6, d = i & 63;
            kv[d * 65 + r] = k[((size_t)bh * Ss + kbase + r) * HDd + d];
        }
        __syncthreads();
        // ---- scores: thread (qg, kl=kk) covers rows qg+4*qi
        {
            float acc[16];
#pragma unroll
            for (int i = 0; i < 16; ++i) acc[i] = 0.f;
            for (int d0 = 0; d0 < 64; d0 += 8) {
                float kreg[8];
#pragma unroll
                for (int j = 0; j < 8; ++j) kreg[j] = kv[(d0 + j) * 65 + kl];
#pragma unroll
                for (int qi = 0; qi < 16; ++qi) {
                    int qq = qg + 4 * qi;
                    float4 a = *(const float4*)&qs[qq * 64 + d0];
                    float4 bq = *(const float4*)&qs[qq * 64 + d0 + 4];
                    acc[qi] += a.x * kreg[0] + a.y * kreg[1] + a.z * kreg[2] + a.w * kreg[3]
                             + bq.x * kreg[4] + bq.y * kreg[5] + bq.z * kreg[6] + bq.w * kreg[7];
                }
            }
            int kpos = kbase + kl;
#pragma unroll
            for (int qi = 0; qi < 16; ++qi) {
                int qq = qg + 4 * qi;
                int qpos = q0 + qq;
                bool valid = (kpos <= qpos);
                if (MODE == 1) valid = valid && (kpos > qpos - WINSZ);
                sc[qq * 68 + kl] = valid ? acc[qi] * SCALE : NEGF;
            }
        }
        __syncthreads();
        // ---- stage V: kv[r*65 + d]  (K no longer needed)
        for (int i = tid; i < 64 * 64; i += 256) {
            int r = i >> 6, d = i & 63;
            kv[r * 65 + d] = v[((size_t)bh * Ss + kbase + r) * HDd + d];
        }
        // ---- softmax: 4 lanes per row (r = tid>>2), 16 cols each
        {
            int r = tid >> 2;
            int c0 = (tid & 3) * 16;
            float mx = NEGF;
#pragma unroll
            for (int cc = 0; cc < 16; cc += 4) {
                float4 sv = *(const float4*)&sc[r * 68 + c0 + cc];
                mx = fmaxf(mx, fmaxf(fmaxf(sv.x, sv.y), fmaxf(sv.z, sv.w)));
            }
            mx = fmaxf(mx, __shfl_xor(mx, 1));
            mx = fmaxf(mx, __shfl_xor(mx, 2));
            float mold = mrow[r];
            float mnew = fmaxf(mold, mx);
            float alpha = expf(mold - mnew);   // NEG-NEG -> exp(0)=1; NEG-fin -> 0
            float sum = 0.f;
#pragma unroll
            for (int cc = 0; cc < 16; ++cc) {
                float sv = sc[r * 68 + c0 + cc];
                float p = (sv <= NEGF * 0.5f) ? 0.f : expf(sv - mnew);
                sc[r * 68 + c0 + cc] = p;
                sum += p;
            }
            sum += __shfl_xor(sum, 1);
            sum += __shfl_xor(sum, 2);
            if ((tid & 3) == 0) {
                lrow[r] = lrow[r] * alpha + sum;
                mrow[r] = mnew;
                arow[r] = alpha;
            }
        }
        __syncthreads();
        // ---- PV: thread (qg, kl=d) accumulates rows qg+4*qi
        {
#pragma unroll
            for (int qi = 0; qi < 16; ++qi) outr[qi] *= arow[qg + 4 * qi];
            for (int kk0 = 0; kk0 < 64; kk0 += 8) {
                float vreg[8];
#pragma unroll
                for (int j = 0; j < 8; ++j) vreg[j] = kv[(kk0 + j) * 65 + kl];
#pragma unroll
                for (int qi = 0; qi < 16; ++qi) {
                    int qq = qg + 4 * qi;
                    float4 p1 = *(const float4*)&sc[qq * 68 + kk0];
                    float4 p2 = *(const float4*)&sc[qq * 68 + kk0 + 4];
                    outr[qi] += p1.x * vreg[0] + p1.y * vreg[1] + p1.z * vreg[2] + p1.w * vreg[3]
                              + p2.x * vreg[4] + p2.y * vreg[5] + p2.z * vreg[6] + p2.w * vreg[7];
                }
            }
        }
        __syncthreads();   // protect kv/sc before next tile
    }
    // epilogue: o += g * out / l   (lsum >= 1: self-key always valid)
#pragma unroll
    for (int qi = 0; qi < 16; ++qi) {
        int qq = qg + 4 * qi;
        int s = q0 + qq;
        float li = lrow[qq];
        float gv = g[((size_t)(b * Ss + s)) * 3 + ((MODE == 0) ? 1 : 2)];
        size_t oi = ((size_t)(b * Ss + s)) * DMm + h * HDd + kl;
        o[oi] += (outr[qi] / li) * gv;
    }
}

// -------------------- K7: y = o @ Wo (tiled 64x64 fp32 GEMM) ------------------
__global__ __launch_bounds__(256) void k_outproj(const float* __restrict__ o,
        const float* __restrict__ Wo, float* __restrict__ y)
{
    const int m0 = blockIdx.x * 64;
    const int n0 = blockIdx.y * 64;
    __shared__ float As[16][68];
    __shared__ float Bs[16][68];
    const int tid = threadIdx.x;
    const int tx = tid & 15, ty = tid >> 4;
    float acc[4][4] = {};
    for (int k0 = 0; k0 < DMm; k0 += 16) {
        {
            int r = tid >> 2;
            int kq = (tid & 3) * 4;
            float4 t4 = *(const float4*)(o + (size_t)(m0 + r) * DMm + k0 + kq);
            As[kq + 0][r] = t4.x;
            As[kq + 1][r] = t4.y;
            As[kq + 2][r] = t4.z;
            As[kq + 3][r] = t4.w;
        }
        {
            int kk = tid >> 4;
            int nq = (tid & 15) * 4;
            float4 t4 = *(const float4*)(Wo + (size_t)(k0 + kk) * DMm + n0 + nq);
            Bs[kk][nq + 0] = t4.x;
            Bs[kk][nq + 1] = t4.y;
            Bs[kk][nq + 2] = t4.z;
            Bs[kk][nq + 3] = t4.w;
        }
        __syncthreads();
#pragma unroll
        for (int kk = 0; kk < 16; ++kk) {
            float4 av = *(const float4*)&As[kk][ty * 4];
            float4 bv = *(const float4*)&Bs[kk][tx * 4];
            acc[0][0] += av.x * bv.x; acc[0][1] += av.x * bv.y; acc[0][2] += av.x * bv.z; acc[0][3] += av.x * bv.w;
            acc[1][0] += av.y * bv.x; acc[1][1] += av.y * bv.y; acc[1][2] += av.y * bv.z; acc[1][3] += av.y * bv.w;
            acc[2][0] += av.z * bv.x; acc[2][1] += av.z * bv.y; acc[2][2] += av.z * bv.z; acc[2][3] += av.z * bv.w;
            acc[3][0] += av.w * bv.x; acc[3][1] += av.w * bv.y; acc[3][2] += av.w * bv.z; acc[3][3] += av.w * bv.w;
        }
        __syncthreads();
    }
#pragma unroll
    for (int i = 0; i < 4; ++i) {
        int m = m0 + ty * 4 + i;
#pragma unroll
        for (int j = 0; j < 4; ++j) {
            int n = n0 + tx * 4 + j;
            y[(size_t)m * DMm + n] = acc[i][j];
        }
    }
}

// -------------------- constant emitter (host-side contract checks) ------------
__global__ __launch_bounds__(256) void k_const(float* __restrict__ y, float val)
{
    int i = blockIdx.x * 256 + threadIdx.x;
    y[i] = val;
}

// -------------------- launch --------------------------------------------------
extern "C" void kernel_launch(void* const* d_in, const int* in_sizes, int n_in,
                              void* d_out, int out_size, void* d_ws, size_t ws_size,
                              hipStream_t stream) {
    float* y = (float*)d_out;
    if (n_in != 6) {
        k_const<<<dim3(16384), 256, 0, stream>>>(y, 88888.f);
        return;
    }
    if (in_sizes[0] != 4194304 || in_sizes[1] != 262144 || in_sizes[2] != 262144 ||
        in_sizes[3] != 262144 || in_sizes[4] != 262144 || in_sizes[5] != 1536) {
        k_const<<<dim3(16384), 256, 0, stream>>>(y, 77777.f);
        return;
    }
    if (ws_size < WS_FLOATS * sizeof(float)) {
        k_const<<<dim3(16384), 256, 0, stream>>>(y, 66666.f);
        return;
    }

    const float* x  = (const float*)d_in[0];
    const float* Wq = (const float*)d_in[1];
    const float* Wk = (const float*)d_in[2];
    const float* Wv = (const float*)d_in[3];
    const float* Wo = (const float*)d_in[4];
    const float* Wg = (const float*)d_in[5];
    float* ws = (float*)d_ws;

    float* qw   = ws + OFF_Q;
    float* kw   = ws + OFF_K;
    float* vw   = ws + OFF_V;
    float* ow   = ws + OFF_O;
    float* gw   = ws + OFF_G;
    float* kcw  = ws + OFF_KC;
    float* vcw  = ws + OFF_VC;
    float* impw = ws + OFF_IMPB;
    int*   selw = (int*)(ws + OFF_SEL);

    k_proj<<<dim3(128, 8, 3), 256, 0, stream>>>(x, Wq, Wk, Wv, ws);
    k_gate<<<dim3(32), 256, 0, stream>>>(x, Wg, gw);
    k_pool<<<dim3(512), 256, 0, stream>>>(kw, vw, kcw, vcw);
    k_zero<<<dim3(256), 256, 0, stream>>>(impw, Bb * Hh * NSs * NSs);
    k_cmp<<<dim3(4096, 16), 64, 0, stream>>>(qw, kcw, vcw, gw, impw, ow);
    k_topk<<<dim3(4), 256, 0, stream>>>(impw, selw);
    k_attn<0><<<dim3(64, 16), 256, 0, stream>>>(qw, kw, vw, selw, gw, ow);
    k_attn<1><<<dim3(64, 16), 256, 0, stream>>>(qw, kw, vw, selw, gw, ow);
    k_outproj<<<dim3(128, 8), 256, 0, stream>>>(ow, Wo, y);
}